// Round 2
// baseline (65.502 us; speedup 1.0000x reference)
//
#include <hip/hip_runtime.h>

constexpr int KSZ     = 16;
constexpr int STRIDE  = 4;
constexpr int NROWS   = 4096;
constexpr int LCOLS   = 8192;
constexpr int OUT_LEN = (LCOLS - KSZ) / STRIDE + 1;  // 2045
constexpr int OPT     = 4;                            // outputs per thread
constexpr int SPAN    = KSZ + (OPT - 1) * STRIDE;     // 28 floats per thread
constexpr int NLOADS  = (SPAN + 3) / 4;               // 7 float4 loads

__global__ __launch_bounds__(512) void or_conv_kernel(
    const float* __restrict__ x, const float* __restrict__ w,
    float* __restrict__ out)
{
    const int t  = threadIdx.x;        // 0..511
    const int n  = blockIdx.x;         // row
    const int o0 = t * OPT;            // first output index of this thread

    // Weights: wave-uniform, constant indices -> SGPR scalar loads.
    float wr[KSZ];
#pragma unroll
    for (int k = 0; k < KSZ; ++k) wr[k] = w[k];

    // Contiguous 28-float span covering 4 overlapping windows.
    // Base = o0*4 floats = 64*t bytes -> 16B aligned.
    const float* rowp = x + (size_t)n * LCOLS;
    const float4* p   = reinterpret_cast<const float4*>(rowp + o0 * STRIDE);

    float win[NLOADS * 4];
#pragma unroll
    for (int j = 0; j < NLOADS; ++j) {
        float4 v;
        if (o0 * STRIDE + j * 4 < LCOLS) {       // guard row tail (thread 511)
            v = p[j];
        } else {
            v = float4{0.f, 0.f, 0.f, 0.f};
        }
        win[4 * j + 0] = v.x; win[4 * j + 1] = v.y;
        win[4 * j + 2] = v.z; win[4 * j + 3] = v.w;
    }

    // rho bounded (|x|<~6, w<=0.7 -> |rho|<~4.2): exp never overflows,
    // skip softmax max-subtraction (mathematically identical).
    float res[OPT];
#pragma unroll
    for (int i = 0; i < OPT; ++i) {
        float se = 0.f, sr = 0.f;
#pragma unroll
        for (int k = 0; k < KSZ; ++k) {
            float rho = win[STRIDE * i + k] * wr[k];
            float e   = __expf(rho);
            se += e;
            sr  = fmaf(rho, e, sr);
        }
        res[i] = sr * __builtin_amdgcn_rcpf(se);  // 1-ulp rcp, threshold 5e-2
    }

    // Row start is only 4B-aligned (2045 % 4 != 0) -> scalar dword stores.
    // Wave writes a fully-contiguous span; L2 write-combines to exact HBM bytes.
    float* op = out + (size_t)n * OUT_LEN + o0;
#pragma unroll
    for (int i = 0; i < OPT; ++i) {
        if (o0 + i < OUT_LEN) __builtin_nontemporal_store(res[i], op + i);
    }
}

extern "C" void kernel_launch(void* const* d_in, const int* in_sizes, int n_in,
                              void* d_out, int out_size, void* d_ws, size_t ws_size,
                              hipStream_t stream)
{
    const float* x = (const float*)d_in[0];
    const float* w = (const float*)d_in[1];
    float* out     = (float*)d_out;

    or_conv_kernel<<<dim3(NROWS), dim3(512), 0, stream>>>(x, w, out);
}

// Round 3
// 38.224 us; speedup vs baseline: 1.7137x; 1.7137x over previous
//
#include <hip/hip_runtime.h>

constexpr int KSZ     = 16;
constexpr int STRIDE  = 4;
constexpr int NROWS   = 4096;
constexpr int LCOLS   = 8192;
constexpr int OUT_LEN = (LCOLS - KSZ) / STRIDE + 1;  // 2045
constexpr int OPT     = 4;                            // outputs per thread
constexpr int SPAN    = KSZ + (OPT - 1) * STRIDE;     // 28 floats per thread
constexpr int NLOADS  = (SPAN + 3) / 4;               // 7 float4 loads

__global__ __launch_bounds__(512) void or_conv_kernel(
    const float* __restrict__ x, const float* __restrict__ w,
    float* __restrict__ out)
{
    const int t  = threadIdx.x;        // 0..511
    const int n  = blockIdx.x;         // row
    const int o0 = t * OPT;            // first output index of this thread

    // Weights: wave-uniform, constant indices -> SGPR scalar loads.
    float wr[KSZ];
#pragma unroll
    for (int k = 0; k < KSZ; ++k) wr[k] = w[k];

    // Contiguous 28-float span covering 4 overlapping windows.
    // Base = o0*4 floats = 64*t bytes -> 16B aligned.
    const float* rowp = x + (size_t)n * LCOLS;
    const float4* p   = reinterpret_cast<const float4*>(rowp + o0 * STRIDE);

    float win[NLOADS * 4];
#pragma unroll
    for (int j = 0; j < NLOADS; ++j) {
        float4 v;
        if (o0 * STRIDE + j * 4 < LCOLS) {       // guard row tail (thread 511)
            v = p[j];
        } else {
            v = float4{0.f, 0.f, 0.f, 0.f};
        }
        win[4 * j + 0] = v.x; win[4 * j + 1] = v.y;
        win[4 * j + 2] = v.z; win[4 * j + 3] = v.w;
    }

    // rho bounded (|x|<~6, w<=0.7 -> |rho|<~4.2): exp never overflows,
    // skip softmax max-subtraction (mathematically identical).
    float res[OPT];
#pragma unroll
    for (int i = 0; i < OPT; ++i) {
        float se = 0.f, sr = 0.f;
#pragma unroll
        for (int k = 0; k < KSZ; ++k) {
            float rho = win[STRIDE * i + k] * wr[k];
            float e   = __expf(rho);
            se += e;
            sr  = fmaf(rho, e, sr);
        }
        res[i] = sr * __builtin_amdgcn_rcpf(se);  // 1-ulp rcp, threshold 5e-2
    }

    // NORMAL cached stores (round-2 lesson: nontemporal scalar stores with
    // lane-stride-16B addresses caused 3.8x HBM write amplification via
    // partial-line RMW; cached stores let L2 merge into full 64B lines).
    float* op = out + (size_t)n * OUT_LEN + o0;
#pragma unroll
    for (int i = 0; i < OPT; ++i) {
        if (o0 + i < OUT_LEN) op[i] = res[i];
    }
}

extern "C" void kernel_launch(void* const* d_in, const int* in_sizes, int n_in,
                              void* d_out, int out_size, void* d_ws, size_t ws_size,
                              hipStream_t stream)
{
    const float* x = (const float*)d_in[0];
    const float* w = (const float*)d_in[1];
    float* out     = (float*)d_out;

    or_conv_kernel<<<dim3(NROWS), dim3(512), 0, stream>>>(x, w, out);
}

// Round 4
// 32.362 us; speedup vs baseline: 2.0241x; 1.1811x over previous
//
#include <hip/hip_runtime.h>

constexpr int KSZ     = 16;
constexpr int STRIDE  = 4;
constexpr int NROWS   = 4096;
constexpr int LCOLS   = 8192;
constexpr int OUT_LEN = (LCOLS - KSZ) / STRIDE + 1;  // 2045
constexpr int BLOCK   = 512;
constexpr int NF4     = LCOLS / 4;                   // 2048 float4 per row

// XOR swizzle on float4 index: spreads the 8 bank-groups so that lanes
// t, t+8, t+16, ... (which alias under linear layout) hit distinct groups.
// Same involution applied on write and read (both-sides rule).
__device__ __forceinline__ int swz(int p) { return p ^ ((p >> 3) & 7); }

__global__ __launch_bounds__(BLOCK) void or_conv_kernel(
    const float* __restrict__ x, const float* __restrict__ w,
    float* __restrict__ out)
{
    __shared__ float4 smem[NF4];   // 32 KB: one full input row

    const int t = threadIdx.x;
    const int n = blockIdx.x;

    // Weights: wave-uniform, constant indices -> SGPR scalar loads.
    float wr[KSZ];
#pragma unroll
    for (int k = 0; k < KSZ; ++k) wr[k] = w[k];

    // Stage row -> LDS. Each load instruction is lane-contiguous float4
    // (16B/lane stride, fully-used cache lines) and each float is read
    // from global exactly once.
    const float4* rowp4 = reinterpret_cast<const float4*>(x + (size_t)n * LCOLS);
#pragma unroll
    for (int j = 0; j < 4; ++j) {
        const int pos = t + BLOCK * j;          // covers 0..2047 exactly
        smem[swz(pos)] = rowp4[pos];
    }
    __syncthreads();

    // Thread t computes outputs t, t+512, t+1024, t+1536 so that each
    // store instruction is lane-contiguous (256B full lines -> nontemporal
    // safe, no RMW; keeps output from evicting L3-resident input).
    float* orow = out + (size_t)n * OUT_LEN;
#pragma unroll
    for (int i = 0; i < 4; ++i) {
        const int o = t + BLOCK * i;
        if (o < OUT_LEN) {
            // Window = floats [4o, 4o+16) = float4 positions o..o+3.
            float win[KSZ];
#pragma unroll
            for (int j = 0; j < 4; ++j) {
                const float4 v = smem[swz(o + j)];
                win[4 * j + 0] = v.x; win[4 * j + 1] = v.y;
                win[4 * j + 2] = v.z; win[4 * j + 3] = v.w;
            }
            // rho bounded (|x|<~6, w<=0.7 -> |rho|<~4.2): exp never
            // overflows; skip softmax max-subtraction (identical math).
            float se = 0.f, sr = 0.f;
#pragma unroll
            for (int k = 0; k < KSZ; ++k) {
                const float rho = win[k] * wr[k];
                const float e   = __expf(rho);
                se += e;
                sr  = fmaf(rho, e, sr);
            }
            __builtin_nontemporal_store(sr * __builtin_amdgcn_rcpf(se), orow + o);
        }
    }
}

extern "C" void kernel_launch(void* const* d_in, const int* in_sizes, int n_in,
                              void* d_out, int out_size, void* d_ws, size_t ws_size,
                              hipStream_t stream)
{
    const float* x = (const float*)d_in[0];
    const float* w = (const float*)d_in[1];
    float* out     = (float*)d_out;

    or_conv_kernel<<<dim3(NROWS), dim3(BLOCK), 0, stream>>>(x, w, out);
}

// Round 5
// 30.875 us; speedup vs baseline: 2.1215x; 1.0481x over previous
//
#include <hip/hip_runtime.h>

constexpr int KSZ     = 16;
constexpr int STRIDE  = 4;
constexpr int NROWS   = 4096;
constexpr int LCOLS   = 8192;
constexpr int OUT_LEN = (LCOLS - KSZ) / STRIDE + 1;  // 2045
constexpr int BLOCK   = 512;
constexpr int NF4     = LCOLS / 4;                   // 2048 float4 per row

// Bijective XOR swizzle on float4 index (low 3 bits ^= f(high bits)).
// Write side (q consecutive per lane): conflict-free (consecutive mod-8 distinct).
// Read side (q = 4*lane + j): lanes {l, l+2, l+8, l+16, l+32} all land in
// distinct bank groups -> uniform 8 lanes per 4-bank group = conflict-free.
__device__ __forceinline__ int swz(int q) {
    return q ^ (((q >> 3) ^ (q >> 6)) & 7);
}

__global__ __launch_bounds__(BLOCK) void or_conv_kernel(
    const float* __restrict__ x, const float* __restrict__ w,
    float* __restrict__ out)
{
    __shared__ float4 smem[NF4];   // 32 KB: one full input row

    const int t = threadIdx.x;
    const int n = blockIdx.x;

    // Pre-scale weights by log2(e): exp(rho) = exp2(rho*log2e), and
    // sum(rho*e) = ln2 * sum(t*e). Saves the hidden mul inside __expf.
    float wr2[KSZ];
#pragma unroll
    for (int k = 0; k < KSZ; ++k) wr2[k] = w[k] * 1.44269504089f;

    // Stage row -> LDS: 4 lane-contiguous float4 loads (1x L1 traffic).
    const float4* rowp4 = reinterpret_cast<const float4*>(x + (size_t)n * LCOLS);
#pragma unroll
    for (int j = 0; j < 4; ++j) {
        const int pos = t + BLOCK * j;          // covers 0..2047 exactly
        smem[swz(pos)] = rowp4[pos];
    }
    __syncthreads();

    // Thread t computes 4 CONSECUTIVE outputs 4t..4t+3: their windows span
    // float4 positions 4t..4t+6 -> only 7 ds_read_b128 per 4 outputs.
    float4 f[7];
#pragma unroll
    for (int j = 0; j < 7; ++j) {
        const int q = min(4 * t + j, NF4 - 1);  // clamp tail (thread 511)
        f[j] = smem[swz(q)];
    }
    const float* win = reinterpret_cast<const float*>(f);  // 28 floats

    float res[4];
#pragma unroll
    for (int i = 0; i < 4; ++i) {
        float se = 0.f, sr = 0.f;
#pragma unroll
        for (int k = 0; k < KSZ; ++k) {
            const float tt = win[STRIDE * i + k] * wr2[k];  // rho*log2e
            const float e  = __builtin_amdgcn_exp2f(tt);
            se += e;
            sr  = fmaf(tt, e, sr);
        }
        // rho*e sum = ln2 * sr ; result = ln2*sr/se
        res[i] = sr * 0.69314718056f * __builtin_amdgcn_rcpf(se);
    }

    // 4 consecutive dword stores, NORMAL cached (L2 merges lane-scatter;
    // round-2 lesson: nontemporal scatter = 3.8x HBM write RMW).
    float* op = out + (size_t)n * OUT_LEN + 4 * t;
#pragma unroll
    for (int i = 0; i < 4; ++i) {
        if (4 * t + i < OUT_LEN) op[i] = res[i];
    }
}

extern "C" void kernel_launch(void* const* d_in, const int* in_sizes, int n_in,
                              void* d_out, int out_size, void* d_ws, size_t ws_size,
                              hipStream_t stream)
{
    const float* x = (const float*)d_in[0];
    const float* w = (const float*)d_in[1];
    float* out     = (float*)d_out;

    or_conv_kernel<<<dim3(NROWS), dim3(BLOCK), 0, stream>>>(x, w, out);
}